// Round 17
// baseline (68.392 us; speedup 1.0000x reference)
//
#include <hip/hip_runtime.h>
#include <hip/hip_bf16.h>
#include <stdint.h>

// Grouped linear: y[z] = coeff * x[z] @ W[idx[z]], idx sorted.
// C=8, U=V=512, Z=32768, fp32 in/out, bf16 MFMA compute.
//
// R17: A staged DIRECTLY from x via global_load_lds with per-lane swizzled
// global source (m173 pattern) into a subtiled fp32 LDS layout -- no x
// pre-convert pass, no reg-staging, no ds_writes, no bank conflicts.
// fp32->bf16 conversion happens after ds_read_b128, in-register (cvt_pk).
// B via global_load_lds from pre-tiled bf16 wsw (w-converter only, ~3us).
// 128x128 tile, BK=32, 4 waves, 2-phase dbuf, full-drain barriers
// (R2's proven cadence), 48 KB LDS -> 3 blocks/CU.

#define Cg 8
#define Ud 512
#define Vd 512
#define Zd 32768

#define BM 128
#define BN 128
#define BK 32
#define KT 16

#define TILE_US 4096             // B tile: 128 x 32 bf16 = 8 KiB
#define NBN 4
#define NBM_MAX 263              // sum ceil(cnt_g/128) <= 256+7
#define GRID_GEMM (NBM_MAX * NBN)    // 1052

#define WSW_US (Cg * NBN * KT * TILE_US)     // 4 MiB of bf16
#define WS_NEEDED ((size_t)WSW_US * 2 + 64)

typedef __attribute__((ext_vector_type(8))) short bf16x8;
typedef __attribute__((ext_vector_type(4))) float f32x4;
typedef __attribute__((ext_vector_type(4))) unsigned short us4;
typedef __attribute__((ext_vector_type(4))) unsigned int u32x4;

typedef __attribute__((address_space(3))) unsigned int lds_uint;
typedef const __attribute__((address_space(1))) unsigned int gbl_uint;

__device__ __forceinline__ unsigned int pk2(float lo, float hi) {
    unsigned short l = __bfloat16_as_ushort(__float2bfloat16(lo));
    unsigned short h = __bfloat16_as_ushort(__float2bfloat16(hi));
    return (unsigned int)l | ((unsigned int)h << 16);
}

// A-LDS layout (fp32, one 16 KiB tile): 16B cells, cell = rt*128 + ko*32 +
// half*16 + rl, holding x[row=rt*16+rl][k=kt*32+ko*8+half*4 .. +3].
// Staging: thread t, instr j -> cell = t + 256j (lane-linear dest = LEGAL
// for global_load_lds; global source per-lane swizzled = LEGAL, m173).
// Frag read (lane l, row-tile R): cells {R*128+l4*32+l15, +16} -> two
// ds_read_b128 at byte R*2048+l4*512+{0,256}+l15*16: 16-lane groups stride
// 16B, conflict-free.
// B subtile layout / frag read: identical to R2/R6 (verified, 0 conflicts).

// ---------------- w converter (+ group starts) ----------------

__global__ __launch_bounds__(256)
void convert_w(const float* __restrict__ w, const int* __restrict__ idx,
               unsigned short* __restrict__ wsw, int* __restrict__ starts)
{
    const int t = blockIdx.x * 256 + threadIdx.x;    // 524288 tasks
    const int g   = t >> 16;
    const int rem = t & 65535;
    const int u0  = (rem >> 9) << 2;                 // 4 k-rows
    const int v   = rem & 511;
    const float* src = w + ((size_t)g << 18) + (size_t)u0 * Vd + v;
    us4 p;
    p[0] = (unsigned short)__bfloat16_as_ushort(__float2bfloat16(src[0]));
    p[1] = (unsigned short)__bfloat16_as_ushort(__float2bfloat16(src[Vd]));
    p[2] = (unsigned short)__bfloat16_as_ushort(__float2bfloat16(src[2 * Vd]));
    p[3] = (unsigned short)__bfloat16_as_ushort(__float2bfloat16(src[3 * Vd]));
    const int r = v & 127, k = u0 & 31;
    const int tile = (g * NBN + (v >> 7)) * KT + (u0 >> 5);
    const int off  = tile * TILE_US
                   + ((r >> 4) << 9) + ((k >> 3) << 7) + ((r & 15) << 3) + (k & 7);
    *(us4*)(wsw + off) = p;

    if (blockIdx.x == 0 && threadIdx.x < 9) {
        const int gq = threadIdx.x;
        int lo = 0;
        if (gq >= 8) lo = Zd;
        else {
            int hi = Zd;
            while (lo < hi) { int mid = (lo + hi) >> 1;
                              if (idx[mid] < gq) lo = mid + 1; else hi = mid; }
        }
        starts[gq] = lo;
    }
}

// ---------------- GEMM ----------------

#define STAGE(KTV, AB, BB) do {                                               \
    _Pragma("unroll")                                                         \
    for (int j_ = 0; j_ < 4; ++j_)                                            \
        __builtin_amdgcn_global_load_lds(                                     \
            (gbl_uint*)(asrc[j_] + (KTV) * BK),                               \
            (lds_uint*)(&Asf[AB][tid * 4 + j_ * 1024]), 16, 0, 0);            \
    {                                                                         \
        const unsigned short* s_ = wB + (size_t)(KTV) * TILE_US;              \
        __builtin_amdgcn_global_load_lds((gbl_uint*)(s_ + bo),                \
                                         (lds_uint*)(&Bs[BB][bo]), 16, 0, 0); \
        __builtin_amdgcn_global_load_lds((gbl_uint*)(s_ + bo + 2048),         \
                                         (lds_uint*)(&Bs[BB][bo + 2048]), 16, 0, 0); \
    } } while (0)

#define CMP(AB, BB) do {                                                      \
    bf16x8 a_[4], b_[4];                                                      \
    _Pragma("unroll")                                                         \
    for (int mi_ = 0; mi_ < 4; ++mi_) {                                       \
        const int R_ = wm4 + mi_;                                             \
        const f32x4 lo_ = *(const f32x4*)(&Asf[AB][R_ * 512 + (l4 << 7) + (l15 << 2)]);        \
        const f32x4 hi_ = *(const f32x4*)(&Asf[AB][R_ * 512 + (l4 << 7) + 64 + (l15 << 2)]);   \
        u32x4 t_;                                                             \
        t_[0] = pk2(lo_[0], lo_[1]); t_[1] = pk2(lo_[2], lo_[3]);             \
        t_[2] = pk2(hi_[0], hi_[1]); t_[3] = pk2(hi_[2], hi_[3]);             \
        a_[mi_] = __builtin_bit_cast(bf16x8, t_);                             \
    }                                                                         \
    _Pragma("unroll")                                                         \
    for (int ni_ = 0; ni_ < 4; ++ni_)                                         \
        b_[ni_] = *(const bf16x8*)(&Bs[BB][((wn4 + ni_) << 9) + fr]);         \
    _Pragma("unroll")                                                         \
    for (int mi_ = 0; mi_ < 4; ++mi_)                                         \
        _Pragma("unroll")                                                     \
        for (int ni_ = 0; ni_ < 4; ++ni_)                                     \
            acc[mi_][ni_] = __builtin_amdgcn_mfma_f32_16x16x32_bf16(          \
                a_[mi_], b_[ni_], acc[mi_][ni_], 0, 0, 0);                    \
  } while (0)

#define WAITBAR0() do {                                                       \
    asm volatile("s_waitcnt vmcnt(0) lgkmcnt(0)" ::: "memory");               \
    __builtin_amdgcn_s_barrier(); } while (0)

__global__ __launch_bounds__(256, 3)
void sgl_gemm(const float* __restrict__ x,
              const unsigned short* __restrict__ wsw,
              const int* __restrict__ starts,
              const float* __restrict__ coeff,
              float* __restrict__ y)
{
    __shared__ unsigned int   Asf[2][4096];      // 2 x 16 KiB fp32 A tiles
    __shared__ unsigned short Bs[2][TILE_US];    // 2 x  8 KiB bf16 B tiles

    const int tid = threadIdx.x, lane = tid & 63, wave = tid >> 6;
    const int l15 = lane & 15, l4 = lane >> 4;

    // bijective XCD swizzle (m204): nwg=1052, q=131, r=4; consecutive wk
    // share bmp -> the 4 bn-blocks of one x-panel land on one XCD (L2 reuse).
    const int bid = blockIdx.x;
    const int xcd = bid & 7, io = bid >> 3;
    const int wk  = (xcd < 4) ? xcd * 132 + io : 528 + (xcd - 4) * 131 + io;
    const int bmp = wk >> 2, bn = wk & 3;

    // locate group for this padded row-block
    int s[9];
#pragma unroll
    for (int i = 0; i < 9; ++i) s[i] = starts[i];
    int g = -1, lblk = 0, ab = 0;
#pragma unroll
    for (int gg = 0; gg < 8; ++gg) {
        const int c  = s[gg + 1] - s[gg];
        const int nb = (c + BM - 1) >> 7;
        if (g < 0 && bmp < ab + nb) { g = gg; lblk = bmp - ab; }
        ab += nb;
    }
    if (g < 0) return;
    const int start = s[g];
    const int cnt   = s[g + 1] - s[g];
    const int j0    = lblk << 7;

    // A staging sources: instr j, cell c = tid + 256j ->
    //   rl=c&15, half=(c>>4)&1, ko=(c>>5)&3, rt=c>>7; row=rt*16+rl (clamped)
    const float* asrc[4];
#pragma unroll
    for (int j = 0; j < 4; ++j) {
        const int c    = tid + 256 * j;
        const int rl   = c & 15;
        const int half = (c >> 4) & 1;
        const int ko   = (c >> 5) & 3;
        const int rt   = c >> 7;
        int row = j0 + rt * 16 + rl;
        if (row >= cnt) row = cnt - 1;
        asrc[j] = x + (size_t)(start + row) * Ud + ko * 8 + half * 4;
    }

    // B: linear gload_lds from pre-tiled ws
    const unsigned short* wB = wsw + (size_t)((g * NBN + bn) * KT) * TILE_US;
    const int bo = tid * 8;

    const int wm4 = (wave >> 1) << 2;
    const int wn4 = (wave & 1) << 2;
    const int fr  = (l4 << 7) + (l15 << 3);

    f32x4 acc[4][4];
#pragma unroll
    for (int mi = 0; mi < 4; ++mi)
#pragma unroll
        for (int ni = 0; ni < 4; ++ni)
            acc[mi][ni] = f32x4{0.f, 0.f, 0.f, 0.f};

    // prologue
    STAGE(0, 0, 0);
    WAITBAR0();

    // 2-phase main loop (R2 cadence): stage kt+1 into buf^1, compute kt,
    // full drain at barrier (implicit cross-block overlap hides it, m114).
#pragma unroll
    for (int kt = 0; kt < KT; ++kt) {
        if (kt + 1 < KT) STAGE(kt + 1, (kt + 1) & 1, (kt + 1) & 1);
        CMP(kt & 1, kt & 1);
        WAITBAR0();
    }

    // epilogue: C/D col=lane&15, row=(lane>>4)*4+q; mask padded rows
    const float cf = coeff[0];
    const bool full = (j0 + BM) <= cnt;
#pragma unroll
    for (int mi = 0; mi < 4; ++mi) {
        const int rb = ((wave >> 1) << 6) + mi * 16 + l4 * 4;
#pragma unroll
        for (int ni = 0; ni < 4; ++ni) {
            const int c = bn * BN + ((wave & 1) << 6) + ni * 16 + l15;
#pragma unroll
            for (int q = 0; q < 4; ++q) {
                if (full || (j0 + rb + q) < cnt)
                    y[(size_t)(start + j0 + rb + q) * Vd + c] = acc[mi][ni][q] * cf;
            }
        }
    }
}

// ---------------- safety-net fallback (ws too small; not expected) --------

__global__ __launch_bounds__(256)
void sgl_naive(const float* __restrict__ w, const float* __restrict__ x,
               const int* __restrict__ idx, const float* __restrict__ coeff,
               float* __restrict__ y)
{
    __shared__ float xs[Ud];
    const int z = blockIdx.x;
    const int g = idx[z];
    for (int u = threadIdx.x; u < Ud; u += 256) xs[u] = x[(size_t)z * Ud + u];
    __syncthreads();
    const float* Wg = w + (size_t)g * (Ud * Vd);
    const float cf = coeff[0];
    for (int v = threadIdx.x; v < Vd; v += 256) {
        float acc = 0.f;
        for (int u = 0; u < Ud; ++u) acc += xs[u] * Wg[(size_t)u * Vd + v];
        y[(size_t)z * Vd + v] = acc * cf;
    }
}

extern "C" void kernel_launch(void* const* d_in, const int* in_sizes, int n_in,
                              void* d_out, int out_size, void* d_ws, size_t ws_size,
                              hipStream_t stream) {
    const float* w     = (const float*)d_in[0];
    const float* x     = (const float*)d_in[1];
    const int*   idx   = (const int*)d_in[2];
    const float* coeff = (const float*)d_in[3];
    float* y = (float*)d_out;

    if (ws_size >= WS_NEEDED) {
        unsigned short* wsw = (unsigned short*)d_ws;
        int* starts = (int*)((char*)d_ws + (size_t)WSW_US * 2);
        hipLaunchKernelGGL(convert_w, dim3(2048), dim3(256), 0, stream,
                           w, idx, wsw, starts);
        hipLaunchKernelGGL(sgl_gemm, dim3(GRID_GEMM), dim3(256), 0, stream,
                           x, wsw, starts, coeff, y);
    } else {
        hipLaunchKernelGGL(sgl_naive, dim3(Zd), dim3(256), 0, stream,
                           w, x, idx, coeff, y);
    }
}

// Round 18
// 54.783 us; speedup vs baseline: 1.2484x; 1.2484x over previous
//
#include <hip/hip_runtime.h>
#include <hip/hip_bf16.h>
#include <stdint.h>

// Grouped linear: y[z] = coeff * x[z] @ W[idx[z]], idx sorted.
// C=8, U=V=512, Z=32768, fp32 in/out, bf16 MFMA compute.
//
// R18: minimum-fabric-traffic shape. Block = 64 rows x FULL 512 cols
// (NBN=1 -> x read exactly once chip-wide); B staged per K-step into LDS
// (32 KB, shared by all 8 waves) from pre-tiled L2-resident bf16 wsw
// (W[g] bf16 = 512 KB << 4 MB L2 -> B re-reads L2-hit, not fabric).
// Fabric ~160 MB vs R11's ~460. A: line-coalesced fp32 loads (8 thr/row)
// -> cvt_pk -> 4 KB ds_write. Full-drain 2-phase barriers (R2 cadence,
// spill-race-immune). 512 thr, 8 waves x (64x64), 72 KB LDS -> 2 blk/CU.

#define Cg 8
#define Ud 512
#define Vd 512
#define Zd 32768

#define BM 64
#define KT 16                    // K-steps of 32

#define BSTEP_US 16384           // B per K-step: 512 cols x 32 k bf16 = 32 KiB
#define ASTEP_US 2048            // A per K-step:  64 rows x 32 k bf16 =  4 KiB
#define NBM_MAX 519              // sum ceil(cnt_g/64) <= 512+7
#define GRID_GEMM NBM_MAX

#define WSW_US (Cg * 8 * KT * 4 * 512)   // [g][vb8][kt16][ct4][512us] = 4 MiB
#define WS_NEEDED ((size_t)WSW_US * 2 + 64)

typedef __attribute__((ext_vector_type(8))) short bf16x8;
typedef __attribute__((ext_vector_type(4))) float f32x4;
typedef __attribute__((ext_vector_type(4))) unsigned short us4;
typedef __attribute__((ext_vector_type(4))) float float4v;

typedef __attribute__((address_space(3))) unsigned int lds_uint;
typedef const __attribute__((address_space(1))) unsigned int gbl_uint;

__device__ __forceinline__ unsigned int pk2(float lo, float hi) {
    unsigned short l = __bfloat16_as_ushort(__float2bfloat16(lo));
    unsigned short h = __bfloat16_as_ushort(__float2bfloat16(hi));
    return (unsigned int)l | ((unsigned int)h << 16);
}

// ---------------- w converter (+ group starts) ----------------
// wsw: [g][vb(8 col-blocks of 64)][kt(16)][ct(4 col-subtiles of 16)][512 us]
// subtile (c 0..15, k 0..31): ((k&31)>>3)*128 + c*8 + (k&7).
// Frag read (lane l): us = l4*128 + l15*8 -> 16 lanes cover 256B contiguous:
// conflict-free ds_read_b128 (R13-verified).

__global__ __launch_bounds__(256)
void convert_w(const float* __restrict__ w, const int* __restrict__ idx,
               unsigned short* __restrict__ wsw, int* __restrict__ starts)
{
    const int t = blockIdx.x * 256 + threadIdx.x;    // 524288 tasks
    const int g   = t >> 16;
    const int rem = t & 65535;
    const int u0  = (rem >> 9) << 2;                 // 4 k-rows
    const int v   = rem & 511;
    const float* src = w + ((size_t)g << 18) + (size_t)u0 * Vd + v;
    us4 p;
    p[0] = (unsigned short)__bfloat16_as_ushort(__float2bfloat16(src[0]));
    p[1] = (unsigned short)__bfloat16_as_ushort(__float2bfloat16(src[Vd]));
    p[2] = (unsigned short)__bfloat16_as_ushort(__float2bfloat16(src[2 * Vd]));
    p[3] = (unsigned short)__bfloat16_as_ushort(__float2bfloat16(src[3 * Vd]));
    const int vb = v >> 6, ct = (v >> 4) & 3, c = v & 15;
    const int kt = u0 >> 5;
    const int off = ((((g * 8 + vb) * KT + kt) * 4 + ct) << 9)
                  + (((u0 & 31) >> 3) << 7) + (c << 3) + (u0 & 7);
    *(us4*)(wsw + off) = p;

    if (blockIdx.x == 0 && threadIdx.x < 9) {
        const int gq = threadIdx.x;
        int lo = 0;
        if (gq >= 8) lo = Zd;
        else {
            int hi = Zd;
            while (lo < hi) { int mid = (lo + hi) >> 1;
                              if (idx[mid] < gq) lo = mid + 1; else hi = mid; }
        }
        starts[gq] = lo;
    }
}

// ---------------- GEMM ----------------

// A stage: thread t -> row r = t>>3 (8 consecutive threads cover one 128B
// line of a row), k-seg ks = (t&7)*4. LDS (bf16 subtile layout, us):
//   (r>>4)*512 + (ks>>3)*128 + (r&15)*8 + (ks&7)   [8B us4 write]
// A frag read (lane l, m-tile mi): As[mi*512 + l4*128 + l15*8] -> b128,
// 16 lanes 256B contiguous, conflict-free.

#define LDA(KTV, R) do {                                                      \
    R = *(const float4v*)(ax + (KTV) * 32); } while (0)

#define CVW(BUF, R) do {                                                      \
    us4 p_;                                                                   \
    unsigned int u0_ = pk2(R[0], R[1]), u1_ = pk2(R[2], R[3]);                \
    p_[0] = (unsigned short)(u0_ & 0xffff); p_[1] = (unsigned short)(u0_ >> 16); \
    p_[2] = (unsigned short)(u1_ & 0xffff); p_[3] = (unsigned short)(u1_ >> 16); \
    *(us4*)(&BUF[awo]) = p_; } while (0)

#define GLB(KTV, BUF) do {                                                    \
    _Pragma("unroll")                                                         \
    for (int j_ = 0; j_ < 4; ++j_)                                            \
        __builtin_amdgcn_global_load_lds(                                     \
            (gbl_uint*)(bsrc[j_] + (size_t)(KTV) * 2048),                     \
            (lds_uint*)(&BUF[(tid & 255) * 8 + ((tid >> 8) + 2 * j_) * 2048]),\
            16, 0, 0); } while (0)

#define CMP(AB, BB) do {                                                      \
    bf16x8 a_[4], b_[4];                                                      \
    _Pragma("unroll")                                                         \
    for (int mi_ = 0; mi_ < 4; ++mi_)                                         \
        a_[mi_] = *(const bf16x8*)(&AB[(mi_ << 9) + fr]);                     \
    _Pragma("unroll")                                                         \
    for (int ni_ = 0; ni_ < 4; ++ni_)                                         \
        b_[ni_] = *(const bf16x8*)(&BB[(wave << 11) + (ni_ << 9) + fr]);      \
    _Pragma("unroll")                                                         \
    for (int mi_ = 0; mi_ < 4; ++mi_)                                         \
        _Pragma("unroll")                                                     \
        for (int ni_ = 0; ni_ < 4; ++ni_)                                     \
            acc[mi_][ni_] = __builtin_amdgcn_mfma_f32_16x16x32_bf16(          \
                a_[mi_], b_[ni_], acc[mi_][ni_], 0, 0, 0);                    \
  } while (0)

#define WAITBAR0() do {                                                       \
    asm volatile("s_waitcnt vmcnt(0) lgkmcnt(0)" ::: "memory");               \
    __builtin_amdgcn_s_barrier(); } while (0)

__global__ __launch_bounds__(512, 4)
void sgl_gemm(const float* __restrict__ x,
              const unsigned short* __restrict__ wsw,
              const int* __restrict__ starts,
              const float* __restrict__ coeff,
              float* __restrict__ y)
{
    __shared__ unsigned short As[2][ASTEP_US];   //  8 KiB
    __shared__ unsigned short Bs[2][BSTEP_US];   // 64 KiB -> 72 total

    const int tid = threadIdx.x, lane = tid & 63, wave = tid >> 6;
    const int l15 = lane & 15, l4 = lane >> 4;
    const int fr  = (l4 << 7) + (l15 << 3);

    // bijective XCD swizzle (m204): nwg=519, q=64, r=7 -> consecutive wk on
    // one XCD share group g (sorted) -> W[g] bf16 (512 KB) L2-resident.
    const int bid = blockIdx.x;
    const int xcd = bid & 7, io = bid >> 3;
    const int wk  = (xcd < 7) ? xcd * 65 + io : 455 + io;
    const int bmp = wk;

    // locate group for this padded 64-row block
    int s[9];
#pragma unroll
    for (int i = 0; i < 9; ++i) s[i] = starts[i];
    int g = -1, lblk = 0, ab = 0;
#pragma unroll
    for (int gg = 0; gg < 8; ++gg) {
        const int c  = s[gg + 1] - s[gg];
        const int nb = (c + BM - 1) >> 6;
        if (g < 0 && bmp < ab + nb) { g = gg; lblk = bmp - ab; }
        ab += nb;
    }
    if (g < 0) return;
    const int start = s[g];
    const int cnt   = s[g + 1] - s[g];
    const int j0    = lblk << 6;

    // A: thread t -> row t>>3, k-seg (t&7)*4 (16B load; 8 thr = full line)
    const int ar = tid >> 3;
    const int ks = (tid & 7) << 2;
    const int rc = (j0 + ar < cnt) ? (j0 + ar) : (cnt - 1);
    const float* ax = x + (size_t)(start + rc) * Ud + ks;
    const int awo = ((ar >> 4) << 9) + ((ks >> 3) << 7) + ((ar & 15) << 3) + (ks & 7);

    // B staging sources: instr j covers vb = (tid>>8) + 2j; inner (tid&255)*8
    const unsigned short* bsrc[4];
#pragma unroll
    for (int j = 0; j < 4; ++j) {
        const int vb = (tid >> 8) + 2 * j;
        bsrc[j] = wsw + (((size_t)(g * 8 + vb) * KT) << 11) + (tid & 255) * 8;
    }

    f32x4 acc[4][4];
#pragma unroll
    for (int mi = 0; mi < 4; ++mi)
#pragma unroll
        for (int ni = 0; ni < 4; ++ni)
            acc[mi][ni] = f32x4{0.f, 0.f, 0.f, 0.f};

    float4v e, o;

    // prologue: tile 0
    LDA(0, e);
    GLB(0, Bs[0]);
    CVW(As[0], e);
    WAITBAR0();

    // main loop (R2 full-drain cadence): issue A+B of kt+1 at the top,
    // compute kt (long; covers the loads), cvt A(kt+1), drain, swap.
#pragma unroll
    for (int kt = 0; kt < KT; ++kt) {
        const int cur = kt & 1, nxt = cur ^ 1;
        if (kt + 1 < KT) {
            if (cur == 0) LDA(kt + 1, o); else LDA(kt + 1, e);
            if (cur == 0) GLB(kt + 1, Bs[1]); else GLB(kt + 1, Bs[0]);
        }
        if (cur == 0) CMP(As[0], Bs[0]); else CMP(As[1], Bs[1]);
        if (kt + 1 < KT) {
            if (cur == 0) CVW(As[1], o); else CVW(As[0], e);
        }
        WAITBAR0();
    }

    // epilogue: C/D col=lane&15, row=(lane>>4)*4+q; mask padded rows
    const float cf = coeff[0];
    const bool full = (j0 + BM) <= cnt;
#pragma unroll
    for (int mi = 0; mi < 4; ++mi) {
        const int rb = mi * 16 + l4 * 4;
#pragma unroll
        for (int ni = 0; ni < 4; ++ni) {
            const int c = wave * 64 + ni * 16 + l15;
#pragma unroll
            for (int q = 0; q < 4; ++q) {
                if (full || (j0 + rb + q) < cnt)
                    y[(size_t)(start + j0 + rb + q) * Vd + c] = acc[mi][ni][q] * cf;
            }
        }
    }
}

// ---------------- safety-net fallback (ws too small; not expected) --------

__global__ __launch_bounds__(256)
void sgl_naive(const float* __restrict__ w, const float* __restrict__ x,
               const int* __restrict__ idx, const float* __restrict__ coeff,
               float* __restrict__ y)
{
    __shared__ float xs[Ud];
    const int z = blockIdx.x;
    const int g = idx[z];
    for (int u = threadIdx.x; u < Ud; u += 256) xs[u] = x[(size_t)z * Ud + u];
    __syncthreads();
    const float* Wg = w + (size_t)g * (Ud * Vd);
    const float cf = coeff[0];
    for (int v = threadIdx.x; v < Vd; v += 256) {
        float acc = 0.f;
        for (int u = 0; u < Ud; ++u) acc += xs[u] * Wg[(size_t)u * Vd + v];
        y[(size_t)z * Vd + v] = acc * cf;
    }
}

extern "C" void kernel_launch(void* const* d_in, const int* in_sizes, int n_in,
                              void* d_out, int out_size, void* d_ws, size_t ws_size,
                              hipStream_t stream) {
    const float* w     = (const float*)d_in[0];
    const float* x     = (const float*)d_in[1];
    const int*   idx   = (const int*)d_in[2];
    const float* coeff = (const float*)d_in[3];
    float* y = (float*)d_out;

    if (ws_size >= WS_NEEDED) {
        unsigned short* wsw = (unsigned short*)d_ws;
        int* starts = (int*)((char*)d_ws + (size_t)WSW_US * 2);
        hipLaunchKernelGGL(convert_w, dim3(2048), dim3(256), 0, stream,
                           w, idx, wsw, starts);
        hipLaunchKernelGGL(sgl_gemm, dim3(GRID_GEMM), dim3(512), 0, stream,
                           x, wsw, starts, coeff, y);
    } else {
        hipLaunchKernelGGL(sgl_naive, dim3(Zd), dim3(256), 0, stream,
                           w, x, idx, coeff, y);
    }
}

// Round 19
// 50.200 us; speedup vs baseline: 1.3624x; 1.0913x over previous
//
#include <hip/hip_runtime.h>
#include <hip/hip_bf16.h>
#include <stdint.h>

// Grouped linear: y[z] = coeff * x[z] @ W[idx[z]], idx sorted.
// C=8, U=V=512, Z=32768, fp32 in/out, bf16 MFMA compute.
//
// R19 = R11 (best measured, 50.4 us) with ONE change: native
// __float2bfloat16 conversion (v_cvt_pk_bf16_f32) instead of the 5-op
// hand-rolled RNE -- shortens the CVW VALU chain, everything else verbatim.
// Structure: 128x128 tile, BK=32, 4 waves, 3 blocks/CU, counted-vmcnt raw
// barriers; A fp32 reg-prefetch 3 sets (2-step cover); B 3-buffer
// global_load_lds ring (2-step cover); vmcnt(10) no-op at barriers.

#define Cg 8
#define Ud 512
#define Vd 512
#define Zd 32768

#define BM 128
#define BN 128
#define BK 32
#define KT 16

#define TILE_US 4096             // 128 x 32 bf16 = 8 KiB
#define NBN 4
#define NBM_MAX 263              // sum ceil(cnt_g/128) <= 256+7
#define GRID_GEMM (NBM_MAX * NBN)    // 1052

#define WSW_US (Cg * NBN * KT * TILE_US)     // 4 MiB of bf16
#define WS_NEEDED ((size_t)WSW_US * 2 + 64)

typedef __attribute__((ext_vector_type(8))) short bf16x8;
typedef __attribute__((ext_vector_type(4))) float f32x4;
typedef __attribute__((ext_vector_type(4))) unsigned short us4;
typedef __attribute__((ext_vector_type(4))) float float4v;
typedef __attribute__((ext_vector_type(4))) unsigned int u32x4;

typedef __attribute__((address_space(3))) unsigned int lds_uint;
typedef const __attribute__((address_space(1))) unsigned int gbl_uint;

__device__ __forceinline__ unsigned int pk2(float lo, float hi) {
    // native casts -> compiler emits v_cvt_pk_bf16_f32 (RNE)
    unsigned short l = __bfloat16_as_ushort(__float2bfloat16(lo));
    unsigned short h = __bfloat16_as_ushort(__float2bfloat16(hi));
    return (unsigned int)l | ((unsigned int)h << 16);
}

// Subtile layout within one [128 r][32 k] tile (ushort offset):
//   (r>>4)*512 + (k>>3)*128 + (r&15)*8 + (k&7)
// Frag read (lane l): byte = rt*1024 + l4*256 + l15*16 -> contiguous 1 KiB
// per frag across the wave: conflict-free ds_read_b128 (R2/R6-verified).

// ---------------- w converter (+ group starts) ----------------

__global__ __launch_bounds__(256)
void convert_w(const float* __restrict__ w, const int* __restrict__ idx,
               unsigned short* __restrict__ wsw, int* __restrict__ starts)
{
    const int t = blockIdx.x * 256 + threadIdx.x;    // 524288 tasks
    const int g   = t >> 16;
    const int rem = t & 65535;
    const int u0  = (rem >> 9) << 2;                 // 4 k-rows
    const int v   = rem & 511;
    const float* src = w + ((size_t)g << 18) + (size_t)u0 * Vd + v;
    us4 p;
    p[0] = (unsigned short)__bfloat16_as_ushort(__float2bfloat16(src[0]));
    p[1] = (unsigned short)__bfloat16_as_ushort(__float2bfloat16(src[Vd]));
    p[2] = (unsigned short)__bfloat16_as_ushort(__float2bfloat16(src[2 * Vd]));
    p[3] = (unsigned short)__bfloat16_as_ushort(__float2bfloat16(src[3 * Vd]));
    const int r = v & 127, k = u0 & 31;
    const int tile = (g * NBN + (v >> 7)) * KT + (u0 >> 5);
    const int off  = tile * TILE_US
                   + ((r >> 4) << 9) + ((k >> 3) << 7) + ((r & 15) << 3) + (k & 7);
    *(us4*)(wsw + off) = p;

    if (blockIdx.x == 0 && threadIdx.x < 9) {
        const int gq = threadIdx.x;
        int lo = 0;
        if (gq >= 8) lo = Zd;
        else {
            int hi = Zd;
            while (lo < hi) { int mid = (lo + hi) >> 1;
                              if (idx[mid] < gq) lo = mid + 1; else hi = mid; }
        }
        starts[gq] = lo;
    }
}

// ---------------- GEMM ----------------

#define LDA(KTV, R) do {                                                      \
    const float* p_ = ax + (KTV) * BK;                                        \
    R[0] = *(const float4v*)(p_);                                             \
    R[1] = *(const float4v*)(p_ + 4);                                         \
    R[2] = *(const float4v*)(p_ + 8);                                         \
    R[3] = *(const float4v*)(p_ + 12); } while (0)

#define CVW(BUF, R) do {                                                      \
    u32x4 w1_, w2_;                                                           \
    w1_[0] = pk2(R[0][0], R[0][1]); w1_[1] = pk2(R[0][2], R[0][3]);           \
    w1_[2] = pk2(R[1][0], R[1][1]); w1_[3] = pk2(R[1][2], R[1][3]);           \
    w2_[0] = pk2(R[2][0], R[2][1]); w2_[1] = pk2(R[2][2], R[2][3]);           \
    w2_[2] = pk2(R[3][0], R[3][1]); w2_[3] = pk2(R[3][2], R[3][3]);           \
    *(u32x4*)(&BUF[aw])       = w1_;                                          \
    *(u32x4*)(&BUF[aw + 128]) = w2_; } while (0)

#define GLB(KTV, J) do {                                                      \
    const unsigned short* s_ = wB + (size_t)(KTV) * TILE_US;                  \
    __builtin_amdgcn_global_load_lds((gbl_uint*)(s_ + bo),                    \
                                     (lds_uint*)(&Bs[J][bo]), 16, 0, 0);      \
    __builtin_amdgcn_global_load_lds((gbl_uint*)(s_ + bo + 2048),             \
                                     (lds_uint*)(&Bs[J][bo + 2048]), 16, 0, 0); \
  } while (0)

#define CMP(ABUF, J) do {                                                     \
    bf16x8 a_[4], b_[4];                                                      \
    _Pragma("unroll")                                                         \
    for (int mi_ = 0; mi_ < 4; ++mi_)                                         \
        a_[mi_] = *(const bf16x8*)(&ABUF[((wm4 + mi_) << 9) + fr]);           \
    _Pragma("unroll")                                                         \
    for (int ni_ = 0; ni_ < 4; ++ni_)                                         \
        b_[ni_] = *(const bf16x8*)(&Bs[J][((wn4 + ni_) << 9) + fr]);          \
    _Pragma("unroll")                                                         \
    for (int mi_ = 0; mi_ < 4; ++mi_)                                         \
        _Pragma("unroll")                                                     \
        for (int ni_ = 0; ni_ < 4; ++ni_)                                     \
            acc[mi_][ni_] = __builtin_amdgcn_mfma_f32_16x16x32_bf16(          \
                a_[mi_], b_[ni_], acc[mi_][ni_], 0, 0, 0);                    \
  } while (0)

#define WAITBAR(N) do {                                                       \
    asm volatile("s_waitcnt vmcnt(" #N ") lgkmcnt(0)" ::: "memory");          \
    __builtin_amdgcn_s_barrier(); } while (0)

#define SBAR() __builtin_amdgcn_sched_barrier(0)

__global__ __launch_bounds__(256, 3)
void sgl_gemm(const float* __restrict__ x,
              const unsigned short* __restrict__ wsw,
              const int* __restrict__ starts,
              const float* __restrict__ coeff,
              float* __restrict__ y)
{
    __shared__ unsigned short As[2][TILE_US];    // 16 KiB
    __shared__ unsigned short Bs[3][TILE_US];    // 24 KiB

    const int tid = threadIdx.x, lane = tid & 63, wave = tid >> 6;
    const int l15 = lane & 15, l4 = lane >> 4;

    // bijective XCD swizzle (m204): nwg=1052, q=131, r=4; consecutive wk
    // share bmp -> the 4 bn-blocks of one x-panel land on one XCD (L2 reuse).
    const int bid = blockIdx.x;
    const int xcd = bid & 7, io = bid >> 3;
    const int wk  = (xcd < 4) ? xcd * 132 + io : 528 + (xcd - 4) * 131 + io;
    const int bmp = wk >> 2, bn = wk & 3;

    // locate group for this padded row-block
    int s[9];
#pragma unroll
    for (int i = 0; i < 9; ++i) s[i] = starts[i];
    int g = -1, lblk = 0, ab = 0;
#pragma unroll
    for (int gg = 0; gg < 8; ++gg) {
        const int c  = s[gg + 1] - s[gg];
        const int nb = (c + BM - 1) >> 7;
        if (g < 0 && bmp < ab + nb) { g = gg; lblk = bmp - ab; }
        ab += nb;
    }
    if (g < 0) return;
    const int start = s[g];
    const int cnt   = s[g + 1] - s[g];
    const int j0    = lblk << 7;

    // A: thread t -> row t>>1 (coalesced pairs), k-half (t&1)*16; clamp pads
    const int ar = tid >> 1;
    const int ak = (tid & 1) << 4;
    const int rc = (j0 + ar < cnt) ? (j0 + ar) : (cnt - 1);
    const float* ax = x + (size_t)(start + rc) * Ud + ak;
    const int aw = ((ar >> 4) << 9) + ((ak >> 3) << 7) + ((ar & 15) << 3);

    // B: linear gload_lds from pre-tiled ws (8 KiB tile, 2 x 16B per thread)
    const unsigned short* wB = wsw + (size_t)((g * NBN + bn) * KT) * TILE_US;
    const int bo = tid * 8;

    const int wm4 = (wave >> 1) << 2;
    const int wn4 = (wave & 1) << 2;
    const int fr  = (l4 << 7) + (l15 << 3);

    f32x4 acc[4][4];
#pragma unroll
    for (int mi = 0; mi < 4; ++mi)
#pragma unroll
        for (int ni = 0; ni < 4; ++ni)
            acc[mi][ni] = f32x4{0.f, 0.f, 0.f, 0.f};

    float4v A0[4], A1[4], A2[4];   // 3 rotating A reg-sets (2-step cover)

    // prologue: B0,B1 + A0,A1,A2 in flight; cvt A(0); barrier.
    GLB(0, 0);
    SBAR();
    LDA(0, A0);
    SBAR();
    GLB(1, 1);
    SBAR();
    LDA(1, A1);
    SBAR();
    LDA(2, A2);
    SBAR();
    CVW(As[0], A0);
    WAITBAR(10);                   // vmcnt no-op; lgkm drain; B0/As0 ready

    // steady kt=0..12: GLB(kt+2), LDA(kt+3) into set kt%3, CVW tile kt+1
    // from set (kt+1)%3, CMP tile kt. Outstanding at barrier = 10.
#pragma unroll
    for (int kt = 0; kt < 13; ++kt) {
        GLB(kt + 2, (kt + 2) % 3);
        SBAR();
        switch (kt % 3) {          // LDA(kt+3) -> set (kt+3)%3 == kt%3
            case 0: LDA(kt + 3, A0); break;
            case 1: LDA(kt + 3, A1); break;
            default: LDA(kt + 3, A2); break;
        }
        SBAR();
        switch ((kt + 1) % 3) {    // CVW tile kt+1 (regs loaded at kt-2)
            case 0: CVW(As[(kt + 1) & 1], A0); break;
            case 1: CVW(As[(kt + 1) & 1], A1); break;
            default: CVW(As[(kt + 1) & 1], A2); break;
        }
        CMP(As[kt & 1], kt % 3);
        WAITBAR(10);
    }
    // kt = 13: GLB(15) only; outstanding at barrier = B(15)+A(15) = 6
    GLB(15, (15) % 3);
    SBAR();
    CVW(As[14 & 1], A2);           // tile 14 -> set 14%3 = 2
    CMP(As[13 & 1], 13 % 3);
    WAITBAR(6);
    // kt = 14: CVW tile 15 (set 15%3=0); auto-wait drains A(15); then bar 0
    CVW(As[15 & 1], A0);
    CMP(As[14 & 1], 14 % 3);
    WAITBAR(0);
    // kt = 15
    CMP(As[15 & 1], 15 % 3);

    // epilogue: C/D col=lane&15, row=(lane>>4)*4+q; mask padded rows
    const float cf = coeff[0];
    const bool full = (j0 + BM) <= cnt;
#pragma unroll
    for (int mi = 0; mi < 4; ++mi) {
        const int rb = ((wave >> 1) << 6) + mi * 16 + l4 * 4;
#pragma unroll
        for (int ni = 0; ni < 4; ++ni) {
            const int c = bn * BN + ((wave & 1) << 6) + ni * 16 + l15;
#pragma unroll
            for (int q = 0; q < 4; ++q) {
                if (full || (j0 + rb + q) < cnt)
                    y[(size_t)(start + j0 + rb + q) * Vd + c] = acc[mi][ni][q] * cf;
            }
        }
    }
}

// ---------------- safety-net fallback (ws too small; not expected) --------

__global__ __launch_bounds__(256)
void sgl_naive(const float* __restrict__ w, const float* __restrict__ x,
               const int* __restrict__ idx, const float* __restrict__ coeff,
               float* __restrict__ y)
{
    __shared__ float xs[Ud];
    const int z = blockIdx.x;
    const int g = idx[z];
    for (int u = threadIdx.x; u < Ud; u += 256) xs[u] = x[(size_t)z * Ud + u];
    __syncthreads();
    const float* Wg = w + (size_t)g * (Ud * Vd);
    const float cf = coeff[0];
    for (int v = threadIdx.x; v < Vd; v += 256) {
        float acc = 0.f;
        for (int u = 0; u < Ud; ++u) acc += xs[u] * Wg[(size_t)u * Vd + v];
        y[(size_t)z * Vd + v] = acc * cf;
    }
}

extern "C" void kernel_launch(void* const* d_in, const int* in_sizes, int n_in,
                              void* d_out, int out_size, void* d_ws, size_t ws_size,
                              hipStream_t stream) {
    const float* w     = (const float*)d_in[0];
    const float* x     = (const float*)d_in[1];
    const int*   idx   = (const int*)d_in[2];
    const float* coeff = (const float*)d_in[3];
    float* y = (float*)d_out;

    if (ws_size >= WS_NEEDED) {
        unsigned short* wsw = (unsigned short*)d_ws;
        int* starts = (int*)((char*)d_ws + (size_t)WSW_US * 2);
        hipLaunchKernelGGL(convert_w, dim3(2048), dim3(256), 0, stream,
                           w, idx, wsw, starts);
        hipLaunchKernelGGL(sgl_gemm, dim3(GRID_GEMM), dim3(256), 0, stream,
                           x, wsw, starts, coeff, y);
    } else {
        hipLaunchKernelGGL(sgl_naive, dim3(Zd), dim3(256), 0, stream,
                           w, x, idx, coeff, y);
    }
}

// Round 20
// 49.640 us; speedup vs baseline: 1.3778x; 1.0113x over previous
//
#include <hip/hip_runtime.h>
#include <hip/hip_bf16.h>
#include <stdint.h>

// Grouped linear: y[z] = coeff * x[z] @ W[idx[z]], idx sorted.
// C=8, U=V=512, Z=32768, fp32 in/out, bf16 MFMA compute.
//
// FINAL (R20 = R19, best measured 50.2 us): 128x128 tile, BK=32, 4 waves,
// 3 blocks/CU, counted-vmcnt raw barriers; A fp32 reg-prefetch 3 sets
// (2-step cover); B 3-buffer global_load_lds ring (2-step cover); native
// v_cvt_pk_bf16_f32 conversion; bijective XCD swizzle; group-padded blocks.
// 19-round ledger: every schedule/tiling/traffic variant lands 50-55 us;
// not HBM-bound (21%), not MFMA-bound (10%); residual stall source not
// attributable with available gfx950 counters.

#define Cg 8
#define Ud 512
#define Vd 512
#define Zd 32768

#define BM 128
#define BN 128
#define BK 32
#define KT 16

#define TILE_US 4096             // 128 x 32 bf16 = 8 KiB
#define NBN 4
#define NBM_MAX 263              // sum ceil(cnt_g/128) <= 256+7
#define GRID_GEMM (NBM_MAX * NBN)    // 1052

#define WSW_US (Cg * NBN * KT * TILE_US)     // 4 MiB of bf16
#define WS_NEEDED ((size_t)WSW_US * 2 + 64)

typedef __attribute__((ext_vector_type(8))) short bf16x8;
typedef __attribute__((ext_vector_type(4))) float f32x4;
typedef __attribute__((ext_vector_type(4))) unsigned short us4;
typedef __attribute__((ext_vector_type(4))) float float4v;
typedef __attribute__((ext_vector_type(4))) unsigned int u32x4;

typedef __attribute__((address_space(3))) unsigned int lds_uint;
typedef const __attribute__((address_space(1))) unsigned int gbl_uint;

__device__ __forceinline__ unsigned int pk2(float lo, float hi) {
    // native casts -> compiler emits v_cvt_pk_bf16_f32 (RNE)
    unsigned short l = __bfloat16_as_ushort(__float2bfloat16(lo));
    unsigned short h = __bfloat16_as_ushort(__float2bfloat16(hi));
    return (unsigned int)l | ((unsigned int)h << 16);
}

// Subtile layout within one [128 r][32 k] tile (ushort offset):
//   (r>>4)*512 + (k>>3)*128 + (r&15)*8 + (k&7)
// Frag read (lane l): byte = rt*1024 + l4*256 + l15*16 -> contiguous 1 KiB
// per frag across the wave: conflict-free ds_read_b128 (R2/R6-verified).

// ---------------- w converter (+ group starts) ----------------

__global__ __launch_bounds__(256)
void convert_w(const float* __restrict__ w, const int* __restrict__ idx,
               unsigned short* __restrict__ wsw, int* __restrict__ starts)
{
    const int t = blockIdx.x * 256 + threadIdx.x;    // 524288 tasks
    const int g   = t >> 16;
    const int rem = t & 65535;
    const int u0  = (rem >> 9) << 2;                 // 4 k-rows
    const int v   = rem & 511;
    const float* src = w + ((size_t)g << 18) + (size_t)u0 * Vd + v;
    us4 p;
    p[0] = (unsigned short)__bfloat16_as_ushort(__float2bfloat16(src[0]));
    p[1] = (unsigned short)__bfloat16_as_ushort(__float2bfloat16(src[Vd]));
    p[2] = (unsigned short)__bfloat16_as_ushort(__float2bfloat16(src[2 * Vd]));
    p[3] = (unsigned short)__bfloat16_as_ushort(__float2bfloat16(src[3 * Vd]));
    const int r = v & 127, k = u0 & 31;
    const int tile = (g * NBN + (v >> 7)) * KT + (u0 >> 5);
    const int off  = tile * TILE_US
                   + ((r >> 4) << 9) + ((k >> 3) << 7) + ((r & 15) << 3) + (k & 7);
    *(us4*)(wsw + off) = p;

    if (blockIdx.x == 0 && threadIdx.x < 9) {
        const int gq = threadIdx.x;
        int lo = 0;
        if (gq >= 8) lo = Zd;
        else {
            int hi = Zd;
            while (lo < hi) { int mid = (lo + hi) >> 1;
                              if (idx[mid] < gq) lo = mid + 1; else hi = mid; }
        }
        starts[gq] = lo;
    }
}

// ---------------- GEMM ----------------

#define LDA(KTV, R) do {                                                      \
    const float* p_ = ax + (KTV) * BK;                                        \
    R[0] = *(const float4v*)(p_);                                             \
    R[1] = *(const float4v*)(p_ + 4);                                         \
    R[2] = *(const float4v*)(p_ + 8);                                         \
    R[3] = *(const float4v*)(p_ + 12); } while (0)

#define CVW(BUF, R) do {                                                      \
    u32x4 w1_, w2_;                                                           \
    w1_[0] = pk2(R[0][0], R[0][1]); w1_[1] = pk2(R[0][2], R[0][3]);           \
    w1_[2] = pk2(R[1][0], R[1][1]); w1_[3] = pk2(R[1][2], R[1][3]);           \
    w2_[0] = pk2(R[2][0], R[2][1]); w2_[1] = pk2(R[2][2], R[2][3]);           \
    w2_[2] = pk2(R[3][0], R[3][1]); w2_[3] = pk2(R[3][2], R[3][3]);           \
    *(u32x4*)(&BUF[aw])       = w1_;                                          \
    *(u32x4*)(&BUF[aw + 128]) = w2_; } while (0)

#define GLB(KTV, J) do {                                                      \
    const unsigned short* s_ = wB + (size_t)(KTV) * TILE_US;                  \
    __builtin_amdgcn_global_load_lds((gbl_uint*)(s_ + bo),                    \
                                     (lds_uint*)(&Bs[J][bo]), 16, 0, 0);      \
    __builtin_amdgcn_global_load_lds((gbl_uint*)(s_ + bo + 2048),             \
                                     (lds_uint*)(&Bs[J][bo + 2048]), 16, 0, 0); \
  } while (0)

#define CMP(ABUF, J) do {                                                     \
    bf16x8 a_[4], b_[4];                                                      \
    _Pragma("unroll")                                                         \
    for (int mi_ = 0; mi_ < 4; ++mi_)                                         \
        a_[mi_] = *(const bf16x8*)(&ABUF[((wm4 + mi_) << 9) + fr]);           \
    _Pragma("unroll")                                                         \
    for (int ni_ = 0; ni_ < 4; ++ni_)                                         \
        b_[ni_] = *(const bf16x8*)(&Bs[J][((wn4 + ni_) << 9) + fr]);          \
    _Pragma("unroll")                                                         \
    for (int mi_ = 0; mi_ < 4; ++mi_)                                         \
        _Pragma("unroll")                                                     \
        for (int ni_ = 0; ni_ < 4; ++ni_)                                     \
            acc[mi_][ni_] = __builtin_amdgcn_mfma_f32_16x16x32_bf16(          \
                a_[mi_], b_[ni_], acc[mi_][ni_], 0, 0, 0);                    \
  } while (0)

#define WAITBAR(N) do {                                                       \
    asm volatile("s_waitcnt vmcnt(" #N ") lgkmcnt(0)" ::: "memory");          \
    __builtin_amdgcn_s_barrier(); } while (0)

#define SBAR() __builtin_amdgcn_sched_barrier(0)

__global__ __launch_bounds__(256, 3)
void sgl_gemm(const float* __restrict__ x,
              const unsigned short* __restrict__ wsw,
              const int* __restrict__ starts,
              const float* __restrict__ coeff,
              float* __restrict__ y)
{
    __shared__ unsigned short As[2][TILE_US];    // 16 KiB
    __shared__ unsigned short Bs[3][TILE_US];    // 24 KiB

    const int tid = threadIdx.x, lane = tid & 63, wave = tid >> 6;
    const int l15 = lane & 15, l4 = lane >> 4;

    // bijective XCD swizzle (m204): nwg=1052, q=131, r=4; consecutive wk
    // share bmp -> the 4 bn-blocks of one x-panel land on one XCD (L2 reuse).
    const int bid = blockIdx.x;
    const int xcd = bid & 7, io = bid >> 3;
    const int wk  = (xcd < 4) ? xcd * 132 + io : 528 + (xcd - 4) * 131 + io;
    const int bmp = wk >> 2, bn = wk & 3;

    // locate group for this padded row-block
    int s[9];
#pragma unroll
    for (int i = 0; i < 9; ++i) s[i] = starts[i];
    int g = -1, lblk = 0, ab = 0;
#pragma unroll
    for (int gg = 0; gg < 8; ++gg) {
        const int c  = s[gg + 1] - s[gg];
        const int nb = (c + BM - 1) >> 7;
        if (g < 0 && bmp < ab + nb) { g = gg; lblk = bmp - ab; }
        ab += nb;
    }
    if (g < 0) return;
    const int start = s[g];
    const int cnt   = s[g + 1] - s[g];
    const int j0    = lblk << 7;

    // A: thread t -> row t>>1 (coalesced pairs), k-half (t&1)*16; clamp pads
    const int ar = tid >> 1;
    const int ak = (tid & 1) << 4;
    const int rc = (j0 + ar < cnt) ? (j0 + ar) : (cnt - 1);
    const float* ax = x + (size_t)(start + rc) * Ud + ak;
    const int aw = ((ar >> 4) << 9) + ((ak >> 3) << 7) + ((ar & 15) << 3);

    // B: linear gload_lds from pre-tiled ws (8 KiB tile, 2 x 16B per thread)
    const unsigned short* wB = wsw + (size_t)((g * NBN + bn) * KT) * TILE_US;
    const int bo = tid * 8;

    const int wm4 = (wave >> 1) << 2;
    const int wn4 = (wave & 1) << 2;
    const int fr  = (l4 << 7) + (l15 << 3);

    f32x4 acc[4][4];
#pragma unroll
    for (int mi = 0; mi < 4; ++mi)
#pragma unroll
        for (int ni = 0; ni < 4; ++ni)
            acc[mi][ni] = f32x4{0.f, 0.f, 0.f, 0.f};

    float4v A0[4], A1[4], A2[4];   // 3 rotating A reg-sets (2-step cover)

    // prologue: B0,B1 + A0,A1,A2 in flight; cvt A(0); barrier.
    GLB(0, 0);
    SBAR();
    LDA(0, A0);
    SBAR();
    GLB(1, 1);
    SBAR();
    LDA(1, A1);
    SBAR();
    LDA(2, A2);
    SBAR();
    CVW(As[0], A0);
    WAITBAR(10);                   // vmcnt no-op; lgkm drain; B0/As0 ready

    // steady kt=0..12: GLB(kt+2), LDA(kt+3) into set kt%3, CVW tile kt+1
    // from set (kt+1)%3, CMP tile kt. FIFO discipline makes WAITBAR(10)
    // exactly drain B(kt+1) while A prefetches stay in flight.
#pragma unroll
    for (int kt = 0; kt < 13; ++kt) {
        GLB(kt + 2, (kt + 2) % 3);
        SBAR();
        switch (kt % 3) {          // LDA(kt+3) -> set (kt+3)%3 == kt%3
            case 0: LDA(kt + 3, A0); break;
            case 1: LDA(kt + 3, A1); break;
            default: LDA(kt + 3, A2); break;
        }
        SBAR();
        switch ((kt + 1) % 3) {    // CVW tile kt+1 (regs loaded at kt-2)
            case 0: CVW(As[(kt + 1) & 1], A0); break;
            case 1: CVW(As[(kt + 1) & 1], A1); break;
            default: CVW(As[(kt + 1) & 1], A2); break;
        }
        CMP(As[kt & 1], kt % 3);
        WAITBAR(10);
    }
    // kt = 13: GLB(15) only; outstanding at barrier = B(15)+A(15) = 6
    GLB(15, (15) % 3);
    SBAR();
    CVW(As[14 & 1], A2);           // tile 14 -> set 14%3 = 2
    CMP(As[13 & 1], 13 % 3);
    WAITBAR(6);
    // kt = 14: CVW tile 15 (set 15%3=0); auto-wait drains A(15); then bar 0
    CVW(As[15 & 1], A0);
    CMP(As[14 & 1], 14 % 3);
    WAITBAR(0);
    // kt = 15
    CMP(As[15 & 1], 15 % 3);

    // epilogue: C/D col=lane&15, row=(lane>>4)*4+q; mask padded rows
    const float cf = coeff[0];
    const bool full = (j0 + BM) <= cnt;
#pragma unroll
    for (int mi = 0; mi < 4; ++mi) {
        const int rb = ((wave >> 1) << 6) + mi * 16 + l4 * 4;
#pragma unroll
        for (int ni = 0; ni < 4; ++ni) {
            const int c = bn * BN + ((wave & 1) << 6) + ni * 16 + l15;
#pragma unroll
            for (int q = 0; q < 4; ++q) {
                if (full || (j0 + rb + q) < cnt)
                    y[(size_t)(start + j0 + rb + q) * Vd + c] = acc[mi][ni][q] * cf;
            }
        }
    }
}

// ---------------- safety-net fallback (ws too small; not expected) --------

__global__ __launch_bounds__(256)
void sgl_naive(const float* __restrict__ w, const float* __restrict__ x,
               const int* __restrict__ idx, const float* __restrict__ coeff,
               float* __restrict__ y)
{
    __shared__ float xs[Ud];
    const int z = blockIdx.x;
    const int g = idx[z];
    for (int u = threadIdx.x; u < Ud; u += 256) xs[u] = x[(size_t)z * Ud + u];
    __syncthreads();
    const float* Wg = w + (size_t)g * (Ud * Vd);
    const float cf = coeff[0];
    for (int v = threadIdx.x; v < Vd; v += 256) {
        float acc = 0.f;
        for (int u = 0; u < Ud; ++u) acc += xs[u] * Wg[(size_t)u * Vd + v];
        y[(size_t)z * Vd + v] = acc * cf;
    }
}

extern "C" void kernel_launch(void* const* d_in, const int* in_sizes, int n_in,
                              void* d_out, int out_size, void* d_ws, size_t ws_size,
                              hipStream_t stream) {
    const float* w     = (const float*)d_in[0];
    const float* x     = (const float*)d_in[1];
    const int*   idx   = (const int*)d_in[2];
    const float* coeff = (const float*)d_in[3];
    float* y = (float*)d_out;

    if (ws_size >= WS_NEEDED) {
        unsigned short* wsw = (unsigned short*)d_ws;
        int* starts = (int*)((char*)d_ws + (size_t)WSW_US * 2);
        hipLaunchKernelGGL(convert_w, dim3(2048), dim3(256), 0, stream,
                           w, idx, wsw, starts);
        hipLaunchKernelGGL(sgl_gemm, dim3(GRID_GEMM), dim3(256), 0, stream,
                           x, wsw, starts, coeff, y);
    } else {
        hipLaunchKernelGGL(sgl_naive, dim3(Zd), dim3(256), 0, stream,
                           w, x, idx, coeff, y);
    }
}